// Round 4
// baseline (260.883 us; speedup 1.0000x reference)
//
#include <hip/hip_runtime.h>

#define Bn 64
#define Cc 384
#define NHh 6
#define HD 64
#define Hh 32
#define Ww 32
#define LQ 1025
#define LKV 257
#define TPAD 288
#define EPSf 1e-5f
#define SCALEf 0.05103103630798288f   // 384^-0.5

typedef float f32x4 __attribute__((ext_vector_type(4)));
typedef unsigned short u16x8 __attribute__((ext_vector_type(8)));
typedef unsigned short u16x4 __attribute__((ext_vector_type(4)));
typedef int i32x4 __attribute__((ext_vector_type(4)));

__device__ __forceinline__ void mfma_16x16x32_bf16(f32x4& d, u16x8 a, u16x8 b) {
  // D = A*B + D ; A: 16x32, row = lane&15, k = (lane>>4)*8 + i (contig 8)
  //              B: 32x16, col = lane&15, k = (lane>>4)*8 + i
  //              D: col = lane&15, row = (lane>>4)*4 + reg
  asm("v_mfma_f32_16x16x32_bf16 %0, %1, %2, %0" : "+v"(d) : "v"(a), "v"(b));
}

__device__ __forceinline__ unsigned short f2bf(float f) {
  unsigned int u = __builtin_bit_cast(unsigned int, f);
  u += 0x7fffu + ((u >> 16) & 1u);
  return (unsigned short)(u >> 16);
}

__device__ __forceinline__ u16x4 f4tobf(f32x4 v, f32x4 inv, f32x4 add) {
  u16x4 r;
#pragma unroll
  for (int i = 0; i < 4; ++i) r[i] = f2bf(v[i] * inv[i] + add[i]);
  return r;
}

// ---------------- zero fill for v_t pad columns t in [256,288) ----------------
__global__ void zero_pad_kernel(unsigned short* v_t) {
  int i = blockIdx.x * 256 + threadIdx.x;            // Bn*Cc*32
  int t = 256 + (i & 31);
  int row = i >> 5;                                   // b*384 + o
  v_t[(size_t)row * TPAD + t] = 0;
}

// ---------------- fp32 -> bf16 weight conversion (GEMM weights) ---------------
__global__ void cvt_w_kernel(const float* wq, const float* wk, const float* wv,
                             unsigned short* dst) {
  int i = blockIdx.x * 256 + threadIdx.x;            // 3*384*384
  int which = i / (Cc * Cc), r = i % (Cc * Cc);
  const float* s = (which == 0) ? wq : (which == 1) ? wk : wv;
  dst[i] = f2bf(s[r]);
}

// ---------------- conv-weight transpose + BN fold -----------------------------
// wT[conv][tap][384] f32 ; bn[conv][2][384] f32 (inv, add)
__global__ void wprep_kernel(const float* cwq, const float* cwk, const float* cwv,
                             const float* gq, const float* bq, const float* mq, const float* vq,
                             const float* gk, const float* bk, const float* mk, const float* vk,
                             const float* gv, const float* bv, const float* mv, const float* vv,
                             float* wT, float* bn) {
  int i = blockIdx.x * 256 + threadIdx.x;
  if (i < 3 * 9 * Cc) {
    int which = i / (9 * Cc), r = i % (9 * Cc), t = r / Cc, c = r % Cc;
    const float* s = (which == 0) ? cwq : (which == 1) ? cwk : cwv;
    wT[(which * 9 + t) * Cc + c] = s[c * 9 + t];
  }
  if (i < 3 * Cc) {
    int which = i / Cc, c = i % Cc;
    const float* g = (which == 0) ? gq : (which == 1) ? gk : gv;
    const float* be = (which == 0) ? bq : (which == 1) ? bk : bv;
    const float* mu = (which == 0) ? mq : (which == 1) ? mk : mv;
    const float* va = (which == 0) ? vq : (which == 1) ? vk : vv;
    float inv = g[c] * rsqrtf(va[c] + EPSf);
    bn[which * 768 + c] = inv;
    bn[which * 768 + 384 + c] = be[c] - mu[c] * inv;
  }
}

// ---------------- cls token copy into activation row 0 ------------------------
__global__ void cls_kernel(const float* hidden, unsigned short* q_act,
                           unsigned short* k_act, unsigned short* v_act) {
  int i = blockIdx.x * 256 + threadIdx.x;            // Bn*Cc
  int b = i / Cc, c = i % Cc;
  unsigned short v = f2bf(hidden[(size_t)b * LQ * Cc + c]);
  q_act[(size_t)b * LQ * Cc + c] = v;
  k_act[(size_t)b * LKV * Cc + c] = v;
  v_act[(size_t)b * LKV * Cc + c] = v;
}

// ---------------- depthwise conv 3x3 s1 + BN for q, float4 over channels ------
__global__ __launch_bounds__(256) void conv_q4_kernel(
    const float* hidden, const float* wT, const float* bn, unsigned short* q_act) {
  int e = blockIdx.x * 256 + threadIdx.x;
  int cg = e % 96; int r = e / 96;
  int j = r % Ww; r /= Ww;
  int band = r % 8; int b = r / 8;
  int c = cg * 4;
  int i0 = band * 4;

  f32x4 w[9];
#pragma unroll
  for (int t = 0; t < 9; ++t) w[t] = *(const f32x4*)&wT[t * Cc + c];

  const f32x4 fz = {0.f, 0.f, 0.f, 0.f};
  f32x4 acc[4] = {fz, fz, fz, fz};
  const float* hb = hidden + (size_t)b * LQ * Cc + Cc + c;
#pragma unroll
  for (int dh = 0; dh < 6; ++dh) {
    int h = i0 - 1 + dh;
    if (h < 0 || h >= Hh) continue;                  // block-uniform
    const float* hr = hb + (size_t)(h * Ww + j) * Cc;
    f32x4 xl = *(const f32x4*)(hr - Cc);             // in-bounds even at j==0
    f32x4 xc = *(const f32x4*)hr;
    f32x4 xr = (j < Ww - 1) ? *(const f32x4*)(hr + Cc) : fz;
    if (j == 0) xl = fz;
#pragma unroll
    for (int dy = 0; dy < 3; ++dy) {
      int oi = dh - dy;                              // compile-time
      if (oi >= 0 && oi < 4)
        acc[oi] += w[dy * 3 + 0] * xl + w[dy * 3 + 1] * xc + w[dy * 3 + 2] * xr;
    }
  }
  f32x4 inv = *(const f32x4*)&bn[c];
  f32x4 add = *(const f32x4*)&bn[384 + c];
#pragma unroll
  for (int oi = 0; oi < 4; ++oi) {
    int pos = (i0 + oi) * Ww + j;
    *(u16x4*)&q_act[((size_t)b * LQ + 1 + pos) * Cc + c] = f4tobf(acc[oi], inv, add);
  }
}

// ---------------- depthwise conv 3x3 s2 + BN for k,v, float4 over channels ----
__global__ __launch_bounds__(256) void conv_kv4_kernel(
    const float* hidden, const float* wT, const float* bn,
    unsigned short* k_act, unsigned short* v_act) {
  int e = blockIdx.x * 256 + threadIdx.x;
  int cg = e % 96; int r = e / 96;
  int j = r % 16; r /= 16;
  int i = r % 16; int b = r / 16;
  int c = cg * 4;

  f32x4 wk[9], wv[9];
#pragma unroll
  for (int t = 0; t < 9; ++t) {
    wk[t] = *(const f32x4*)&wT[(9 + t) * Cc + c];
    wv[t] = *(const f32x4*)&wT[(18 + t) * Cc + c];
  }
  const f32x4 fz = {0.f, 0.f, 0.f, 0.f};
  f32x4 acck = fz, accv = fz;
  const float* hb = hidden + (size_t)b * LQ * Cc + Cc + c;
#pragma unroll
  for (int dy = 0; dy < 3; ++dy) {
    int h = 2 * i + dy - 1;
    if (h < 0 || h >= Hh) continue;                  // block-uniform
#pragma unroll
    for (int dx = 0; dx < 3; ++dx) {
      int w2 = 2 * j + dx - 1;                       // only j==0,dx==0 underflows
      f32x4 x = *(const f32x4*)(hb + (size_t)(h * Ww + w2) * Cc);
      if (dx == 0 && j == 0) x = fz;
      acck += wk[dy * 3 + dx] * x;
      accv += wv[dy * 3 + dx] * x;
    }
  }
  f32x4 invk = *(const f32x4*)&bn[768 + c];
  f32x4 addk = *(const f32x4*)&bn[768 + 384 + c];
  f32x4 invv = *(const f32x4*)&bn[1536 + c];
  f32x4 addv = *(const f32x4*)&bn[1536 + 384 + c];
  int pos = i * 16 + j;
  *(u16x4*)&k_act[((size_t)b * LKV + 1 + pos) * Cc + c] = f4tobf(acck, invk, addk);
  *(u16x4*)&v_act[((size_t)b * LKV + 1 + pos) * Cc + c] = f4tobf(accv, invv, addv);
}

// ---------------- projection GEMM, m97-style: 128x128 tile, BK=64 -------------
// global_load_lds staging (linear LDS dest, inverse-swizzled global source),
// XOR-swizzled ds_read_b128 frag reads (rule 21: both sides or neither).
// out[m,o] = sum_c A[m,c]*W[o,c] + bias[o]
// mode 0 (q): out[m*384 + o]
// mode 1 (k): bb=m/257, t=m%257 -> out[(bb*288+t)*384 + o]
// mode 2 (v): bb=m/257, t=m%257 -> out[(bb*384+o)*288 + t]
__global__ __launch_bounds__(256) void proj_gemm2_kernel(
    const unsigned short* A, const unsigned short* Wb, const float* bias,
    unsigned short* out, int M, int mode) {
  __shared__ __align__(16) unsigned short A_s[128 * 64];
  __shared__ __align__(16) unsigned short B_s[128 * 64];
  int m0 = blockIdx.x * 128;
  int n0 = blockIdx.y * 128;
  int tid = threadIdx.x;
  int lane = tid & 63, wid = tid >> 6;
  int wm = wid >> 1, wn = wid & 1;
  int lr = lane & 15, lg = lane >> 4;

  const f32x4 fz = {0.f, 0.f, 0.f, 0.f};
  f32x4 acc[4][4];
#pragma unroll
  for (int i = 0; i < 4; ++i)
#pragma unroll
    for (int j = 0; j < 4; ++j) acc[i][j] = fz;

  // staging: 16 chunks of 1 KiB each (8 rows x 128 B); wave handles 4 chunks.
  // lane: row_in_chunk = lane/8, slot = lane%8; LDS linear; source col-slot
  // pre-swizzled so LDS[row][slot] holds global col-slot (slot ^ (row&7)).
  int sric = lane >> 3;                         // row in chunk = row & 7
  int scol = ((lane & 7) ^ sric) << 3;          // source col element offset

  for (int kk = 0; kk < Cc; kk += 64) {
    __syncthreads();                            // prev-step reads complete
#pragma unroll
    for (int i = 0; i < 4; ++i) {
      int chunk = wid * 4 + i;
      int arow = m0 + chunk * 8 + sric;
      if (arow > M - 1) arow = M - 1;
      const unsigned short* ga = &A[(size_t)arow * Cc + kk + scol];
      __builtin_amdgcn_global_load_lds(
          (const __attribute__((address_space(1))) void*)ga,
          (__attribute__((address_space(3))) void*)&A_s[chunk * 512], 16, 0, 0);
      int brow = n0 + chunk * 8 + sric;         // N=384 exact, no clamp
      const unsigned short* gb = &Wb[(size_t)brow * Cc + kk + scol];
      __builtin_amdgcn_global_load_lds(
          (const __attribute__((address_space(1))) void*)gb,
          (__attribute__((address_space(3))) void*)&B_s[chunk * 512], 16, 0, 0);
    }
    __syncthreads();                            // drains vmcnt(0) -> data landed

#pragma unroll
    for (int kc = 0; kc < 2; ++kc) {
      u16x8 af[4], bf2[4];
#pragma unroll
      for (int mi = 0; mi < 4; ++mi) {
        int r = wm * 64 + mi * 16 + lr;
        af[mi] = *(const u16x8*)((const char*)A_s + r * 128 +
                                 (((lg + 4 * kc) ^ (r & 7)) << 4));
      }
#pragma unroll
      for (int ni = 0; ni < 4; ++ni) {
        int r = wn * 64 + ni * 16 + lr;
        bf2[ni] = *(const u16x8*)((const char*)B_s + r * 128 +
                                  (((lg + 4 * kc) ^ (r & 7)) << 4));
      }
#pragma unroll
      for (int mi = 0; mi < 4; ++mi)
#pragma unroll
        for (int ni = 0; ni < 4; ++ni)
          mfma_16x16x32_bf16(acc[mi][ni], af[mi], bf2[ni]);
    }
  }

#pragma unroll
  for (int ni = 0; ni < 4; ++ni) {
    int col = n0 + wn * 64 + ni * 16 + lr;
    float bv = bias[col];
#pragma unroll
    for (int mi = 0; mi < 4; ++mi) {
      int rowbase = m0 + wm * 64 + mi * 16 + lg * 4;
#pragma unroll
      for (int rg = 0; rg < 4; ++rg) {
        int row = rowbase + rg;
        if (row >= M) continue;
        unsigned short bv16 = f2bf(acc[mi][ni][rg] + bv);
        if (mode == 0) {
          out[(size_t)row * Cc + col] = bv16;
        } else {
          int bb = row / LKV, t = row % LKV;
          if (mode == 1) out[((size_t)bb * TPAD + t) * Cc + col] = bv16;
          else           out[((size_t)bb * Cc + col) * TPAD + t] = bv16;
        }
      }
    }
  }
}

// ---------------- fused attention: LDS K/V, swapped QK^T, in-register P -------
// grid (4, NH, B); block = 4 waves.
// K_s: [288][64] bf16, XOR-swizzled (byte ^= (row&7)<<4)
// V_s: [64][296] bf16 (d-major, t padded)
// P relayout: cvt_pk_bf16 + permlane32_swap + permlane16_swap (no LDS round-trip)
__global__ __launch_bounds__(256) void attn_kernel(
    const unsigned short* q_proj, const unsigned short* k_proj,
    const unsigned short* v_t, float* out) {
  __shared__ __align__(16) unsigned short K_s[288 * 64];
  __shared__ __align__(16) unsigned short V_s[64][296];
  int tid = threadIdx.x;
  int wid = tid >> 6, lane = tid & 63;
  int lr = lane & 15, lg = lane >> 4;
  int h = blockIdx.y, b = blockIdx.z, bx = blockIdx.x;

  // ---- cooperative staging ----
  const unsigned short* kg = k_proj + (size_t)b * TPAD * Cc + h * HD;
  const unsigned short* vg = v_t + ((size_t)b * Cc + h * HD) * TPAD;
#pragma unroll
  for (int i = 0; i < 9; ++i) {
    int c = tid + i * 256;
    int row = c >> 3, c16 = c & 7;
    u16x8 kv = *(const u16x8*)&kg[(size_t)row * Cc + c16 * 8];
    *(u16x8*)((char*)K_s + row * 128 + ((c16 * 16) ^ ((row & 7) << 4))) = kv;
    int rv = c / 36, cv = c - rv * 36;
    u16x8 vv = *(const u16x8*)&vg[(size_t)rv * TPAD + cv * 8];
    *(u16x8*)((char*)&V_s[rv][0] + cv * 16) = vv;
  }
  __syncthreads();

  int start = (bx == 0) ? 0 : 1 + bx * 16;            // 65 = 17+16+16+16
  int end = 17 + bx * 16;
  const f32x4 fz = {0.f, 0.f, 0.f, 0.f};

  for (int qt = start + wid; qt < end; qt += 4) {
    int qbase = qt * 16;
    int qrow = qbase + lr; if (qrow > LQ - 1) qrow = LQ - 1;
    const u16x8* qp =
        (const u16x8*)&q_proj[((size_t)b * LQ + qrow) * Cc + h * HD + lg * 8];
    u16x8 q0 = qp[0], q1 = qp[4];

    // ---- QK^T swapped: lane (lr,lg) holds s for q=lr, t = 16T + lg*4 + rg ----
    int kb0 = lr * 128 + ((lg * 16) ^ ((lr & 7) << 4));
    int kb1 = kb0 ^ 64;
    f32x4 s[18];
#pragma unroll
    for (int T = 0; T < 18; ++T) {
      u16x8 ka = *(const u16x8*)((const char*)K_s + kb0 + T * 2048);
      u16x8 kc = *(const u16x8*)((const char*)K_s + kb1 + T * 2048);
      s[T] = fz;
      mfma_16x16x32_bf16(s[T], ka, q0);
      mfma_16x16x32_bf16(s[T], kc, q1);
    }

    // ---- softmax over t for this lane's q-row ----
    float m = -1e30f;
#pragma unroll
    for (int T = 0; T < 18; ++T)
#pragma unroll
      for (int rg = 0; rg < 4; ++rg) {
        int t = T * 16 + lg * 4 + rg;
        float v = (t < LKV) ? s[T][rg] * SCALEf : -1e30f;
        s[T][rg] = v;
        m = fmaxf(m, v);
      }
    m = fmaxf(m, __shfl_xor(m, 16, 64));
    m = fmaxf(m, __shfl_xor(m, 32, 64));
    float sum = 0.f;
#pragma unroll
    for (int T = 0; T < 18; ++T)
#pragma unroll
      for (int rg = 0; rg < 4; ++rg) {
        float p = __expf(s[T][rg] - m);               // masked -> 0
        s[T][rg] = p;
        sum += p;
      }
    sum += __shfl_xor(sum, 16, 64);
    sum += __shfl_xor(sum, 32, 64);

    // ---- PV with in-register P relayout (cvt_pk + permlane swaps) ----
    // target A-frag: lane (lr,lg) needs P[q=lr][kk*32 + lg*8 + i], i=0..7
    f32x4 o[4];
#pragma unroll
    for (int dt = 0; dt < 4; ++dt) o[dt] = fz;
#pragma unroll
    for (int kk = 0; kk < 9; ++kk) {
      int c00, c01, c10, c11;
      asm("v_cvt_pk_bf16_f32 %0, %1, %2"
          : "=v"(c00) : "v"(s[2 * kk][0]), "v"(s[2 * kk][1]));
      asm("v_cvt_pk_bf16_f32 %0, %1, %2"
          : "=v"(c01) : "v"(s[2 * kk][2]), "v"(s[2 * kk][3]));
      asm("v_cvt_pk_bf16_f32 %0, %1, %2"
          : "=v"(c10) : "v"(s[2 * kk + 1][0]), "v"(s[2 * kk + 1][1]));
      asm("v_cvt_pk_bf16_f32 %0, %1, %2"
          : "=v"(c11) : "v"(s[2 * kk + 1][2]), "v"(s[2 * kk + 1][3]));
      // stage 1: swap 32-lane halves between (c00,c10) and (c01,c11)
      asm("v_permlane32_swap_b32 %0, %1" : "+v"(c00), "+v"(c10));
      asm("v_permlane32_swap_b32 %0, %1" : "+v"(c01), "+v"(c11));
      // stage 2: swap 16-lane rows between (c00,c10) and (c01,c11)
      asm("v_permlane16_swap_b32 %0, %1" : "+v"(c00), "+v"(c10));
      asm("v_permlane16_swap_b32 %0, %1" : "+v"(c01), "+v"(c11));
      i32x4 pv = {c00, c01, c10, c11};
      u16x8 pa = __builtin_bit_cast(u16x8, pv);
#pragma unroll
      for (int dt = 0; dt < 4; ++dt) {
        u16x8 vb = *(const u16x8*)&V_s[dt * 16 + lr][kk * 32 + lg * 8];
        mfma_16x16x32_bf16(o[dt], pa, vb);
      }
    }

    // ---- epilogue: o col=d=lr, row=q=lg*4+rg ----
    float rs = 1.0f / sum;
#pragma unroll
    for (int rg = 0; rg < 4; ++rg) {
      int row = qbase + lg * 4 + rg;
      float rsv = __shfl(rs, lg * 4 + rg, 64);
      if (row <= LQ - 1) {
#pragma unroll
        for (int dt = 0; dt < 4; ++dt)
          out[((size_t)b * LQ + row) * Cc + h * HD + dt * 16 + lr] = o[dt][rg] * rsv;
      }
    }
  }
}

extern "C" void kernel_launch(void* const* d_in, const int* in_sizes, int n_in,
                              void* d_out, int out_size, void* d_ws, size_t ws_size,
                              hipStream_t stream) {
  const float* hidden   = (const float*)d_in[0];
  const float* conv_q_w = (const float*)d_in[1];
  const float* bn_q_g   = (const float*)d_in[2];
  const float* bn_q_b   = (const float*)d_in[3];
  const float* bn_q_m   = (const float*)d_in[4];
  const float* bn_q_v   = (const float*)d_in[5];
  const float* w_q      = (const float*)d_in[6];
  const float* b_q      = (const float*)d_in[7];
  const float* conv_k_w = (const float*)d_in[8];
  const float* bn_k_g   = (const float*)d_in[9];
  const float* bn_k_b   = (const float*)d_in[10];
  const float* bn_k_m   = (const float*)d_in[11];
  const float* bn_k_v   = (const float*)d_in[12];
  const float* w_k      = (const float*)d_in[13];
  const float* b_k      = (const float*)d_in[14];
  const float* conv_v_w = (const float*)d_in[15];
  const float* bn_v_g   = (const float*)d_in[16];
  const float* bn_v_b   = (const float*)d_in[17];
  const float* bn_v_m   = (const float*)d_in[18];
  const float* bn_v_v   = (const float*)d_in[19];
  const float* w_v      = (const float*)d_in[20];
  const float* b_v      = (const float*)d_in[21];
  float* out = (float*)d_out;

  char* ws = (char*)d_ws;
  unsigned short* q_act  = (unsigned short*)(ws + 0);          // 65600*384
  unsigned short* k_act  = (unsigned short*)(ws + 50380800);   // 16448*384
  unsigned short* v_act  = (unsigned short*)(ws + 63012864);   // 16448*384
  unsigned short* q_proj = (unsigned short*)(ws + 75644928);   // 65600*384
  unsigned short* k_proj = (unsigned short*)(ws + 126025728);  // 64*288*384
  unsigned short* v_t    = (unsigned short*)(ws + 140181504);  // 64*384*288
  unsigned short* wbf    = (unsigned short*)(ws + 154337280);  // 3*384*384
  float*          wT     = (float*)(ws + 155222016);           // 3*9*384 f32
  float*          bnp    = (float*)(ws + 155263488);           // 3*2*384 f32

  zero_pad_kernel<<<(Bn * Cc * 32) / 256, 256, 0, stream>>>(v_t);
  cvt_w_kernel<<<(3 * Cc * Cc) / 256, 256, 0, stream>>>(w_q, w_k, w_v, wbf);
  wprep_kernel<<<41, 256, 0, stream>>>(conv_q_w, conv_k_w, conv_v_w,
      bn_q_g, bn_q_b, bn_q_m, bn_q_v,
      bn_k_g, bn_k_b, bn_k_m, bn_k_v,
      bn_v_g, bn_v_b, bn_v_m, bn_v_v, wT, bnp);
  cls_kernel<<<(Bn * Cc) / 256, 256, 0, stream>>>(hidden, q_act, k_act, v_act);
  conv_q4_kernel<<<(Bn * 8 * Ww * 96) / 256, 256, 0, stream>>>(hidden, wT, bnp, q_act);
  conv_kv4_kernel<<<(Bn * 16 * 16 * 96) / 256, 256, 0, stream>>>(
      hidden, wT, bnp, k_act, v_act);

  dim3 gq(513, 3);   // ceil(65600/128)=513
  proj_gemm2_kernel<<<gq, 256, 0, stream>>>(q_act, wbf, b_q, q_proj, Bn * LQ, 0);
  dim3 gkv(129, 3);  // ceil(16448/128)=129
  proj_gemm2_kernel<<<gkv, 256, 0, stream>>>(k_act, wbf + Cc * Cc, b_k, k_proj,
                                             Bn * LKV, 1);
  proj_gemm2_kernel<<<gkv, 256, 0, stream>>>(v_act, wbf + 2 * Cc * Cc, b_v, v_t,
                                             Bn * LKV, 2);

  dim3 ga(4, NHh, Bn);
  attn_kernel<<<ga, 256, 0, stream>>>(q_proj, k_proj, v_t, out);
}